// Round 2
// baseline (847.563 us; speedup 1.0000x reference)
//
#include <hip/hip_runtime.h>
#include <hip/hip_bf16.h>

#define N_NODES 50000
#define N_EDGES 1600000
#define NB 782            // buckets of 64 dst nodes: ceil(50000/64)
#define NBB 256           // binning blocks
#define CHUNK 6250        // N_EDGES / NBB (exact)

// ---------------- helpers ----------------
__device__ __forceinline__ int rlanei(int v, int l) {
  return __builtin_amdgcn_readlane(v, l);
}
__device__ __forceinline__ float rlanef(float v, int l) {
  return __int_as_float(__builtin_amdgcn_readlane(__float_as_int(v), l));
}

// ---------------- pass 1: per-(bucket,block) histogram ----------------
// cnt[b*NBB + blk] = #edges in block blk's chunk with dst in bucket b.
__global__ void k_hist(const int* __restrict__ ei, int* __restrict__ cnt) {
  __shared__ int h[NB];
  int tid = threadIdx.x, blk = blockIdx.x;
  for (int i = tid; i < NB; i += 256) h[i] = 0;
  __syncthreads();
  int base = blk * CHUNK;
  for (int i = base + tid; i < base + CHUNK; i += 256)
    atomicAdd(&h[ei[N_EDGES + i] >> 6], 1);
  __syncthreads();
  for (int b = tid; b < NB; b += 256) cnt[b * NBB + blk] = h[b];
}

// ---------------- scan of cnt[NB*NBB] (bucket-major) ----------------
// scan block j == bucket j (NBB == 256 == scan width). bsum[j] = bucket size.
__global__ void k_scanA(const int* __restrict__ cnt, int* __restrict__ bsum) {
  __shared__ int sm[256];
  int t = threadIdx.x;
  sm[t] = cnt[blockIdx.x * 256 + t];
  __syncthreads();
  for (int off = 128; off > 0; off >>= 1) {
    if (t < off) sm[t] += sm[t + off];
    __syncthreads();
  }
  if (t == 0) bsum[blockIdx.x] = sm[0];
}

__global__ void k_scanB(const int* __restrict__ bsum, int* __restrict__ boff) {
  __shared__ int sm[1024];
  int t = threadIdx.x;
  int v = (t < NB) ? bsum[t] : 0;
  sm[t] = v;
  __syncthreads();
  for (int off = 1; off < 1024; off <<= 1) {
    int u = (t >= off) ? sm[t - off] : 0;
    __syncthreads();
    sm[t] += u;
    __syncthreads();
  }
  if (t < NB) boff[t] = sm[t] - v;  // exclusive bucket start
}

// in-place: cnt[b*256+blk] -> global output offset for (bucket b, block blk)
__global__ void k_scanC(int* __restrict__ cnt, const int* __restrict__ boff) {
  __shared__ int sm[256];
  int t = threadIdx.x, j = blockIdx.x;
  int v = cnt[j * 256 + t];
  sm[t] = v;
  __syncthreads();
  for (int off = 1; off < 256; off <<= 1) {
    int u = (t >= off) ? sm[t - off] : 0;
    __syncthreads();
    sm[t] += u;
    __syncthreads();
  }
  cnt[j * 256 + t] = boff[j] + sm[t] - v;  // exclusive within bucket
}

// ---------------- pass 2: binned scatter (block-private regions) ----------
__global__ void k_bin(const int* __restrict__ ei, const int* __restrict__ offs,
                      int* __restrict__ bins) {
  __shared__ int cur[NB];
  int tid = threadIdx.x, blk = blockIdx.x;
  for (int b = tid; b < NB; b += 256) cur[b] = offs[b * NBB + blk];
  __syncthreads();
  int base = blk * CHUNK;
  for (int i = base + tid; i < base + CHUNK; i += 256) {
    int s = ei[i];
    int d = ei[N_EDGES + i];
    int b = d >> 6;
    int p = atomicAdd(&cur[b], 1);
    bins[p] = s | ((d & 63) << 16);   // src < 65536 fits 16 bits
  }
}

// ---------------- per-bucket degree -> dinv (no global atomics) ----------
__global__ void k_dinv(const int* __restrict__ bins, const int* __restrict__ boff,
                       float* __restrict__ dinv) {
  __shared__ int dg[64];
  int tid = threadIdx.x, b = blockIdx.x;
  if (tid < 64) dg[tid] = 0;
  __syncthreads();
  int start = boff[b];
  int end = (b == NB - 1) ? N_EDGES : boff[b + 1];
  for (int i = start + tid; i < end; i += 256)
    atomicAdd(&dg[bins[i] >> 16], 1);
  __syncthreads();
  if (tid < 64) {
    int v = b * 64 + tid;
    if (v < N_NODES) dinv[v] = rsqrtf((float)dg[tid] + 2.0f);
  }
}

// ---------------- weight composition (unchanged) ----------------
__global__ void k_compose(const float* __restrict__ Wz, const float* __restrict__ bz,
                          const float* __restrict__ Wlz, const float* __restrict__ blz,
                          const float* __restrict__ Wh, const float* __restrict__ bh,
                          const float* __restrict__ Wlh, const float* __restrict__ blh,
                          float2* __restrict__ M, float2* __restrict__ B2) {
  int t = blockIdx.x * 256 + threadIdx.x;
  if (t < 4096) {
    int i = t >> 6, c = t & 63;
    float mz = 0.f, mh = 0.f;
    for (int j = 0; j < 64; ++j) {
      mz = fmaf(Wz[i * 64 + j], Wlz[j * 64 + c], mz);
      mh = fmaf(Wh[i * 64 + j], Wlh[j * 64 + c], mh);
    }
    M[t] = make_float2(mz, mh);
  } else if (t < 4160) {
    int c = t - 4096;
    float vz = blz[c], vh = blh[c];
    for (int j = 0; j < 64; ++j) {
      vz = fmaf(bz[j], Wlz[j * 64 + c], vz);
      vh = fmaf(bh[j], Wlh[j * 64 + c], vh);
    }
    B2[c] = make_float2(vz, vh);
  }
}

// ---------------- fused bucket aggregate + cell + readout ----------------
// One block per bucket of 64 nodes. LDS agg[64][64] accumulated with
// ds_add_f32; epilogue computes Z/H~/readout for the bucket's nodes.
__global__ __launch_bounds__(256, 2) void k_agg_b(
    const float* __restrict__ x, const int* __restrict__ bins,
    const int* __restrict__ boff, const float* __restrict__ dinv,
    const float2* __restrict__ M, const float2* __restrict__ B2,
    const float* __restrict__ Wout, const float* __restrict__ bout,
    float* __restrict__ out) {
  __shared__ float agg[4096];   // 16 KB  [dl*64 + c]
  __shared__ float2 sM[4096];   // 32 KB  (Mz,Mh interleaved, [k*64+c])
  __shared__ float sW[2880];    // 11.25 KB (W_out [k*45+c])
  __shared__ float2 sB[64];
  __shared__ float sbo[48];
  int tid = threadIdx.x;
  for (int i = tid; i < 4096; i += 256) { agg[i] = 0.f; sM[i] = M[i]; }
  for (int i = tid; i < 2880; i += 256) sW[i] = Wout[i];
  if (tid < 64) sB[tid] = B2[tid];
  if (tid < 45) sbo[tid] = bout[tid];
  __syncthreads();

  int lane = tid & 63;
  int wv = tid >> 6;
  int b = blockIdx.x;
  int nb = b * 64;
  int start = boff[b];
  int end = (b == NB - 1) ? N_EDGES : boff[b + 1];

  // ---- edge accumulation: agg[dl][:] += dinv[src] * x[src][:] ----
  for (int e0 = start + wv * 64; e0 < end; e0 += 256) {
    int idx = e0 + lane;
    int pk = (idx < end) ? bins[idx] : 0;
    float dvL = (idx < end) ? dinv[pk & 0xFFFF] : 0.f;
    int m = min(64, end - e0);
    if (m == 64) {
      #pragma unroll 8
      for (int j = 0; j < 64; ++j) {
        int p = rlanei(pk, j);
        float dv = rlanef(dvL, j);
        int s = p & 0xFFFF;
        int dl = p >> 16;
        atomicAdd(&agg[dl * 64 + lane], dv * x[s * 64 + lane]);
      }
    } else {
      for (int j = 0; j < m; ++j) {
        int p = rlanei(pk, j);
        float dv = rlanef(dvL, j);
        int s = p & 0xFFFF;
        int dl = p >> 16;
        atomicAdd(&agg[dl * 64 + lane], dv * x[s * 64 + lane]);
      }
    }
  }
  __syncthreads();

  // ---- epilogue: each wave handles 16 nodes, 4 at a time ----
  for (int g = 0; g < 4; ++g) {
    int dl0 = wv * 16 + g * 4;
    float sx[4];
    #pragma unroll
    for (int n = 0; n < 4; ++n) {
      int dl = dl0 + n;
      int v = nb + dl;
      if (v < N_NODES) {
        float dv = dinv[v];
        sx[n] = dv * (agg[dl * 64 + lane] + 2.f * dv * x[v * 64 + lane]);
      } else {
        sx[n] = 0.f;
      }
    }
    float z[4], h[4];
    #pragma unroll
    for (int n = 0; n < 4; ++n) { z[n] = sB[lane].x; h[n] = sB[lane].y; }
    #pragma unroll 8
    for (int k = 0; k < 64; ++k) {
      float2 wvv = sM[k * 64 + lane];
      #pragma unroll
      for (int n = 0; n < 4; ++n) {
        float sk = rlanef(sx[n], k);
        z[n] = fmaf(sk, wvv.x, z[n]);
        h[n] = fmaf(sk, wvv.y, h[n]);
      }
    }
    #pragma unroll
    for (int n = 0; n < 4; ++n) {
      float Z = 1.f / (1.f + __expf(-z[n]));
      float t = fminf(15.f, fmaxf(-15.f, h[n]));
      float e2 = __expf(-2.f * t);
      float Th = (1.f - e2) / (1.f + e2);
      sx[n] = fmaxf((1.f - Z) * Th, 0.f);   // relu(H), H = (1-Z)*tanh
    }
    float o[4] = {0.f, 0.f, 0.f, 0.f};
    #pragma unroll 8
    for (int k = 0; k < 64; ++k) {
      float wvv = (lane < 45) ? sW[k * 45 + lane] : 0.f;
      #pragma unroll
      for (int n = 0; n < 4; ++n) {
        float hk = rlanef(sx[n], k);
        o[n] = fmaf(hk, wvv, o[n]);
      }
    }
    if (lane < 45) {
      #pragma unroll
      for (int n = 0; n < 4; ++n) {
        int v = nb + dl0 + n;
        if (v < N_NODES) out[v * 45 + lane] = o[n] + sbo[lane];
      }
    }
  }
}

// ---------------- launch ----------------
extern "C" void kernel_launch(void* const* d_in, const int* in_sizes, int n_in,
                              void* d_out, int out_size, void* d_ws, size_t ws_size,
                              hipStream_t stream) {
  const float* x    = (const float*)d_in[0];
  const int*   ei   = (const int*)d_in[1];
  const float* Wz   = (const float*)d_in[2];
  const float* bz   = (const float*)d_in[3];
  const float* Wlz  = (const float*)d_in[4];
  const float* blz  = (const float*)d_in[5];
  // d_in[6..9] (W_r branch) are dead: H=0 => H*R=0.
  const float* Wh   = (const float*)d_in[10];
  const float* bh   = (const float*)d_in[11];
  const float* Wlh  = (const float*)d_in[12];
  const float* blh  = (const float*)d_in[13];
  const float* Wout = (const float*)d_in[14];
  const float* bout = (const float*)d_in[15];
  float* out = (float*)d_out;

  char* w = (char*)d_ws;
  int*    cnt  = (int*)(w + 0);          // NB*NBB = 200192 ints (scan in-place)
  int*    bsum = (int*)(w + 800768);     // 782 ints
  int*    boff = (int*)(w + 804096);     // 782 ints
  float*  dinv = (float*)(w + 807424);   // 50000 floats
  float2* M    = (float2*)(w + 1007616); // 4096 float2 (32 KB)
  float2* B2   = (float2*)(w + 1040384); // 64 float2
  int*    bins = (int*)(w + 1041152);    // 1.6M ints (6.4 MB)
  // total ~7.45 MB of ws

  k_hist <<<NBB, 256, 0, stream>>>(ei, cnt);
  k_scanA<<<NB, 256, 0, stream>>>(cnt, bsum);
  k_scanB<<<1, 1024, 0, stream>>>(bsum, boff);
  k_scanC<<<NB, 256, 0, stream>>>(cnt, boff);
  k_bin  <<<NBB, 256, 0, stream>>>(ei, cnt, bins);
  k_dinv <<<NB, 256, 0, stream>>>(bins, boff, dinv);
  k_compose<<<17, 256, 0, stream>>>(Wz, bz, Wlz, blz, Wh, bh, Wlh, blh, M, B2);
  k_agg_b<<<NB, 256, 0, stream>>>(x, bins, boff, dinv, M, B2, Wout, bout, out);
}

// Round 3
// 256.491 us; speedup vs baseline: 3.3044x; 3.3044x over previous
//
#include <hip/hip_runtime.h>
#include <hip/hip_bf16.h>

#define N_NODES 50000
#define N_EDGES 1600000
#define NB 782            // buckets of 64 dst nodes: ceil(50000/64)
#define NBB 256           // binning blocks
#define CHUNK 6250        // N_EDGES / NBB (exact)
#define ZROW 50000        // dummy src row (all zeros) for padding

typedef unsigned short ushort_t;

// ---------------- helpers ----------------
__device__ __forceinline__ int rlanei(int v, int l) {
  return __builtin_amdgcn_readlane(v, l);
}
__device__ __forceinline__ float rlanef(float v, int l) {
  return __int_as_float(__builtin_amdgcn_readlane(__float_as_int(v), l));
}

// ---------------- pass 1: per-(bucket,block) histogram ----------------
__global__ void k_hist(const int* __restrict__ ei, int* __restrict__ cnt) {
  __shared__ int h[NB];
  int tid = threadIdx.x, blk = blockIdx.x;
  for (int i = tid; i < NB; i += 256) h[i] = 0;
  __syncthreads();
  int base = blk * CHUNK;
  for (int i = base + tid; i < base + CHUNK; i += 256)
    atomicAdd(&h[ei[N_EDGES + i] >> 6], 1);
  __syncthreads();
  for (int b = tid; b < NB; b += 256) cnt[b * NBB + blk] = h[b];
}

// ---------------- scans ----------------
__global__ void k_scanA(const int* __restrict__ cnt, int* __restrict__ bsum) {
  __shared__ int sm[256];
  int t = threadIdx.x;
  sm[t] = cnt[blockIdx.x * 256 + t];
  __syncthreads();
  for (int off = 128; off > 0; off >>= 1) {
    if (t < off) sm[t] += sm[t + off];
    __syncthreads();
  }
  if (t == 0) bsum[blockIdx.x] = sm[0];
}

__global__ void k_scanB(const int* __restrict__ bsum, int* __restrict__ boff) {
  __shared__ int sm[1024];
  int t = threadIdx.x;
  int v = (t < NB) ? bsum[t] : 0;
  sm[t] = v;
  __syncthreads();
  for (int off = 1; off < 1024; off <<= 1) {
    int u = (t >= off) ? sm[t - off] : 0;
    __syncthreads();
    sm[t] += u;
    __syncthreads();
  }
  if (t < NB) boff[t] = sm[t] - v;  // exclusive bucket start
  if (t == 0) boff[NB] = N_EDGES;
}

__global__ void k_scanC(int* __restrict__ cnt, const int* __restrict__ boff) {
  __shared__ int sm[256];
  int t = threadIdx.x, j = blockIdx.x;
  int v = cnt[j * 256 + t];
  sm[t] = v;
  __syncthreads();
  for (int off = 1; off < 256; off <<= 1) {
    int u = (t >= off) ? sm[t - off] : 0;
    __syncthreads();
    sm[t] += u;
    __syncthreads();
  }
  cnt[j * 256 + t] = boff[j] + sm[t] - v;
}

// ---------------- pass 2: binned scatter (block-private regions) ----------
__global__ void k_bin(const int* __restrict__ ei, const int* __restrict__ offs,
                      int* __restrict__ bins) {
  __shared__ int cur[NB];
  int tid = threadIdx.x, blk = blockIdx.x;
  for (int b = tid; b < NB; b += 256) cur[b] = offs[b * NBB + blk];
  __syncthreads();
  int base = blk * CHUNK;
  for (int i = base + tid; i < base + CHUNK; i += 256) {
    int s = ei[i];
    int d = ei[N_EDGES + i];
    int b = d >> 6;
    int p = atomicAdd(&cur[b], 1);
    bins[p] = s | ((d & 63) << 16);   // src < 65536 fits 16 bits
  }
}

// ---------------- per-bucket sort -> padded per-node CSR + dinv + xp ------
// One block per bucket of 64 nodes. Per-node lists padded to mult of 8 with
// dummy src ZROW. Also writes xp[v] = dinv[v]*x[v] for its nodes.
__global__ __launch_bounds__(256, 4) void k_sort(
    const int* __restrict__ bins, const int* __restrict__ boff,
    const float* __restrict__ x,
    ushort_t* __restrict__ srcp, int2* __restrict__ rowiv,
    float* __restrict__ dinv, float* __restrict__ xp) {
  __shared__ int dg[64], lo[64], cur[64];
  __shared__ float sdin[64];
  __shared__ int Tsh;
  __shared__ ushort_t buf[8192];
  int tid = threadIdx.x, b = blockIdx.x;
  int start = boff[b], end = boff[b + 1];
  if (tid < 64) dg[tid] = 0;
  __syncthreads();
  for (int i = start + tid; i < end; i += 256)
    atomicAdd(&dg[bins[i] >> 16], 1);
  __syncthreads();
  int pdv = 0;
  if (tid < 64) { pdv = (dg[tid] + 7) & ~7; lo[tid] = pdv; }
  __syncthreads();
  for (int off = 1; off < 64; off <<= 1) {
    int u = 0;
    if (tid < 64 && tid >= off) u = lo[tid - off];
    __syncthreads();
    if (tid < 64) lo[tid] += u;
    __syncthreads();
  }
  int ex = 0;
  if (tid < 64) {
    ex = lo[tid] - pdv;       // exclusive padded offset
    cur[tid] = ex;
    if (tid == 63) Tsh = lo[63];
  }
  __syncthreads();
  int T = Tsh;
  int base = start + b * 512;  // 512 >= 64*7 max padding slack per bucket
  // init padded slots to dummy
  for (int i = tid; i < T; i += 256) buf[i] = (ushort_t)ZROW;
  __syncthreads();
  // scatter within bucket
  for (int i = start + tid; i < end; i += 256) {
    int v = bins[i];
    int dl = v >> 16;
    int p = atomicAdd(&cur[dl], 1);
    buf[p] = (ushort_t)(v & 0xFFFF);
  }
  __syncthreads();
  // coalesced writeout
  for (int i = tid; i < T; i += 256) srcp[base + i] = buf[i];
  // per-node metadata
  if (tid < 64) {
    int v = b * 64 + tid;
    if (v < N_NODES) {
      rowiv[v] = make_int2(base + ex, pdv);
      float dv = rsqrtf((float)dg[tid] + 2.0f);
      dinv[v] = dv;
      sdin[tid] = dv;
    } else {
      sdin[tid] = 0.f;
    }
  }
  __syncthreads();
  // premultiplied rows for this bucket's nodes (coalesced)
  int nb64 = b * 4096;  // b*64*64
  for (int idx = tid; idx < 4096; idx += 256) {
    int v = b * 64 + (idx >> 6);
    if (v < N_NODES) xp[nb64 + idx] = sdin[idx >> 6] * x[nb64 + idx];
  }
  if (b == 0 && tid < 64) xp[ZROW * 64 + tid] = 0.f;  // zero dummy row
}

// ---------------- weight composition ----------------
__global__ void k_compose(const float* __restrict__ Wz, const float* __restrict__ bz,
                          const float* __restrict__ Wlz, const float* __restrict__ blz,
                          const float* __restrict__ Wh, const float* __restrict__ bh,
                          const float* __restrict__ Wlh, const float* __restrict__ blh,
                          float2* __restrict__ M, float2* __restrict__ B2) {
  int t = blockIdx.x * 256 + threadIdx.x;
  if (t < 4096) {
    int i = t >> 6, c = t & 63;
    float mz = 0.f, mh = 0.f;
    for (int j = 0; j < 64; ++j) {
      mz = fmaf(Wz[i * 64 + j], Wlz[j * 64 + c], mz);
      mh = fmaf(Wh[i * 64 + j], Wlh[j * 64 + c], mh);
    }
    M[t] = make_float2(mz, mh);
  } else if (t < 4160) {
    int c = t - 4096;
    float vz = blz[c], vh = blh[c];
    for (int j = 0; j < 64; ++j) {
      vz = fmaf(bz[j], Wlz[j * 64 + c], vz);
      vh = fmaf(bh[j], Wlh[j * 64 + c], vh);
    }
    B2[c] = make_float2(vz, vh);
  }
}

// ---------------- gather: one wave per node, register accumulate ----------
// sx[v][c] = dinv[v]*sum_e xp[src_e][c] + 2*dinv[v]*xp[v][c]
__global__ __launch_bounds__(256) void k_agg(
    const ushort_t* __restrict__ srcp, const int2* __restrict__ rowiv,
    const float* __restrict__ dinv, const float* __restrict__ xp,
    float* __restrict__ sxg) {
  int tid = threadIdx.x;
  int lane = tid & 63;
  int w = blockIdx.x * 4 + (tid >> 6);
  int nw = gridDim.x * 4;
  for (int v = w; v < N_NODES; v += nw) {
    int vu = __builtin_amdgcn_readfirstlane(v);
    int2 ri = rowiv[vu];
    int beg = ri.x, pd = ri.y;
    float a0 = 0.f, a1 = 0.f;
    for (int e = beg; e < beg + pd; e += 64) {
      int rem = beg + pd - e;
      int m = rem < 64 ? rem : 64;   // multiple of 8
      int sv = ZROW;
      if (lane < m) sv = srcp[e + lane];
      for (int j = 0; j < m; j += 8) {
        int s0 = rlanei(sv, j),     s1 = rlanei(sv, j + 1);
        int s2 = rlanei(sv, j + 2), s3 = rlanei(sv, j + 3);
        int s4 = rlanei(sv, j + 4), s5 = rlanei(sv, j + 5);
        int s6 = rlanei(sv, j + 6), s7 = rlanei(sv, j + 7);
        a0 += xp[s0 * 64 + lane];
        a1 += xp[s1 * 64 + lane];
        a0 += xp[s2 * 64 + lane];
        a1 += xp[s3 * 64 + lane];
        a0 += xp[s4 * 64 + lane];
        a1 += xp[s5 * 64 + lane];
        a0 += xp[s6 * 64 + lane];
        a1 += xp[s7 * 64 + lane];
      }
    }
    float dv = dinv[vu];
    float self = xp[vu * 64 + lane];
    sxg[vu * 64 + lane] = dv * (a0 + a1) + 2.f * dv * self;
  }
}

// ---------------- cell + readout ----------------
__global__ __launch_bounds__(256, 3) void k_cell(
    const float* __restrict__ sxg,
    const float2* __restrict__ M, const float2* __restrict__ B2,
    const float* __restrict__ Wout, const float* __restrict__ bout,
    float* __restrict__ out) {
  __shared__ float2 sM[4096];   // 32 KB
  __shared__ float sW[2880];    // 11.25 KB
  __shared__ float2 sB[64];
  __shared__ float sbo[48];
  int tid = threadIdx.x;
  for (int i = tid; i < 4096; i += 256) sM[i] = M[i];
  for (int i = tid; i < 2880; i += 256) sW[i] = Wout[i];
  if (tid < 64) sB[tid] = B2[tid];
  if (tid < 45) sbo[tid] = bout[tid];
  __syncthreads();

  int lane = tid & 63;
  int wv = tid >> 6;
  int nb = blockIdx.x * 64;

  for (int g = 0; g < 4; ++g) {
    int dl0 = wv * 16 + g * 4;
    float sx[4];
    #pragma unroll
    for (int n = 0; n < 4; ++n) {
      int v = nb + dl0 + n;
      sx[n] = (v < N_NODES) ? sxg[v * 64 + lane] : 0.f;
    }
    float z[4], h[4];
    #pragma unroll
    for (int n = 0; n < 4; ++n) { z[n] = sB[lane].x; h[n] = sB[lane].y; }
    #pragma unroll 8
    for (int k = 0; k < 64; ++k) {
      float2 wvv = sM[k * 64 + lane];
      #pragma unroll
      for (int n = 0; n < 4; ++n) {
        float sk = rlanef(sx[n], k);
        z[n] = fmaf(sk, wvv.x, z[n]);
        h[n] = fmaf(sk, wvv.y, h[n]);
      }
    }
    #pragma unroll
    for (int n = 0; n < 4; ++n) {
      float Z = 1.f / (1.f + __expf(-z[n]));
      float t = fminf(15.f, fmaxf(-15.f, h[n]));
      float e2 = __expf(-2.f * t);
      float Th = (1.f - e2) / (1.f + e2);
      sx[n] = fmaxf((1.f - Z) * Th, 0.f);   // relu((1-Z)*tanh(h))
    }
    float o[4] = {0.f, 0.f, 0.f, 0.f};
    #pragma unroll 8
    for (int k = 0; k < 64; ++k) {
      float wvv = (lane < 45) ? sW[k * 45 + lane] : 0.f;
      #pragma unroll
      for (int n = 0; n < 4; ++n) {
        float hk = rlanef(sx[n], k);
        o[n] = fmaf(hk, wvv, o[n]);
      }
    }
    if (lane < 45) {
      #pragma unroll
      for (int n = 0; n < 4; ++n) {
        int v = nb + dl0 + n;
        if (v < N_NODES) out[v * 45 + lane] = o[n] + sbo[lane];
      }
    }
  }
}

// ---------------- launch ----------------
extern "C" void kernel_launch(void* const* d_in, const int* in_sizes, int n_in,
                              void* d_out, int out_size, void* d_ws, size_t ws_size,
                              hipStream_t stream) {
  const float* x    = (const float*)d_in[0];
  const int*   ei   = (const int*)d_in[1];
  const float* Wz   = (const float*)d_in[2];
  const float* bz   = (const float*)d_in[3];
  const float* Wlz  = (const float*)d_in[4];
  const float* blz  = (const float*)d_in[5];
  // d_in[6..9] (W_r branch) dead: H=0 => H*R=0.
  const float* Wh   = (const float*)d_in[10];
  const float* bh   = (const float*)d_in[11];
  const float* Wlh  = (const float*)d_in[12];
  const float* blh  = (const float*)d_in[13];
  const float* Wout = (const float*)d_in[14];
  const float* bout = (const float*)d_in[15];
  float* out = (float*)d_out;

  char* w = (char*)d_ws;
  // region [0, 12.8MB): cnt+bins early, sxg late (no temporal overlap)
  int*      cnt   = (int*)(w + 0);            // 200192 ints (0.8 MB)
  int*      bins  = (int*)(w + 800768);       // 1.6M ints (6.4 MB)
  float*    sxg   = (float*)(w + 0);          // 12.8 MB (aliases cnt+bins)
  ushort_t* srcp  = (ushort_t*)(w + 12800000);// (2000384+128)*2 = ~4.0 MB
  int2*     rowiv = (int2*)(w + 16801024);    // 50000*8 = 0.4 MB
  float*    dinv  = (float*)(w + 17201024);   // 0.2 MB
  int*      bsum  = (int*)(w + 17401024);     // 782 ints
  int*      boff  = (int*)(w + 17404160);     // 783 ints
  float2*   M     = (float2*)(w + 17407360);  // 32 KB
  float2*   B2    = (float2*)(w + 17440128);  // 512 B
  float*    xp    = (float*)(w + 17440768);   // 50001*64*4 = 12.8 MB
  // total ~30.3 MB

  k_hist <<<NBB, 256, 0, stream>>>(ei, cnt);
  k_scanA<<<NB, 256, 0, stream>>>(cnt, bsum);
  k_scanB<<<1, 1024, 0, stream>>>(bsum, boff);
  k_scanC<<<NB, 256, 0, stream>>>(cnt, boff);
  k_bin  <<<NBB, 256, 0, stream>>>(ei, cnt, bins);
  k_sort <<<NB, 256, 0, stream>>>(bins, boff, x, srcp, rowiv, dinv, xp);
  k_compose<<<17, 256, 0, stream>>>(Wz, bz, Wlz, blz, Wh, bh, Wlh, blh, M, B2);
  k_agg  <<<2048, 256, 0, stream>>>(srcp, rowiv, dinv, xp, sxg);
  k_cell <<<NB, 256, 0, stream>>>(sxg, M, B2, Wout, bout, out);
}

// Round 4
// 237.172 us; speedup vs baseline: 3.5736x; 1.0815x over previous
//
#include <hip/hip_runtime.h>
#include <hip/hip_fp16.h>

#define N_NODES 50000
#define N_EDGES 1600000
#define NB 782            // buckets of 64 dst nodes: ceil(50000/64)
#define NBB 256           // binning blocks
#define CHUNK 6250        // N_EDGES / NBB (exact)
#define ZROW 50000        // dummy src row (all zeros) for padding

typedef unsigned short ushort_t;

// ---------------- helpers ----------------
__device__ __forceinline__ int rlanei(int v, int l) {
  return __builtin_amdgcn_readlane(v, l);
}
__device__ __forceinline__ float rlanef(float v, int l) {
  return __int_as_float(__builtin_amdgcn_readlane(__float_as_int(v), l));
}

// ---------------- pass 1: per-(bucket,block) histogram ----------------
__global__ void k_hist(const int* __restrict__ ei, int* __restrict__ cnt) {
  __shared__ int h[NB];
  int tid = threadIdx.x, blk = blockIdx.x;
  for (int i = tid; i < NB; i += 256) h[i] = 0;
  __syncthreads();
  int base = blk * CHUNK;
  for (int i = base + tid; i < base + CHUNK; i += 256)
    atomicAdd(&h[ei[N_EDGES + i] >> 6], 1);
  __syncthreads();
  for (int b = tid; b < NB; b += 256) cnt[b * NBB + blk] = h[b];
}

// ---------------- scans ----------------
__global__ void k_scanA(const int* __restrict__ cnt, int* __restrict__ bsum) {
  __shared__ int sm[256];
  int t = threadIdx.x;
  sm[t] = cnt[blockIdx.x * 256 + t];
  __syncthreads();
  for (int off = 128; off > 0; off >>= 1) {
    if (t < off) sm[t] += sm[t + off];
    __syncthreads();
  }
  if (t == 0) bsum[blockIdx.x] = sm[0];
}

__global__ void k_scanB(const int* __restrict__ bsum, int* __restrict__ boff) {
  __shared__ int sm[1024];
  int t = threadIdx.x;
  int v = (t < NB) ? bsum[t] : 0;
  sm[t] = v;
  __syncthreads();
  for (int off = 1; off < 1024; off <<= 1) {
    int u = (t >= off) ? sm[t - off] : 0;
    __syncthreads();
    sm[t] += u;
    __syncthreads();
  }
  if (t < NB) boff[t] = sm[t] - v;  // exclusive bucket start
  if (t == 0) boff[NB] = N_EDGES;
}

__global__ void k_scanC(int* __restrict__ cnt, const int* __restrict__ boff) {
  __shared__ int sm[256];
  int t = threadIdx.x, j = blockIdx.x;
  int v = cnt[j * 256 + t];
  sm[t] = v;
  __syncthreads();
  for (int off = 1; off < 256; off <<= 1) {
    int u = (t >= off) ? sm[t - off] : 0;
    __syncthreads();
    sm[t] += u;
    __syncthreads();
  }
  cnt[j * 256 + t] = boff[j] + sm[t] - v;
}

// ---------------- pass 2: binned scatter (block-private regions) ----------
__global__ void k_bin(const int* __restrict__ ei, const int* __restrict__ offs,
                      int* __restrict__ bins) {
  __shared__ int cur[NB];
  int tid = threadIdx.x, blk = blockIdx.x;
  for (int b = tid; b < NB; b += 256) cur[b] = offs[b * NBB + blk];
  __syncthreads();
  int base = blk * CHUNK;
  for (int i = base + tid; i < base + CHUNK; i += 256) {
    int s = ei[i];
    int d = ei[N_EDGES + i];
    int b = d >> 6;
    int p = atomicAdd(&cur[b], 1);
    bins[p] = s | ((d & 63) << 16);   // src < 65536 fits 16 bits
  }
}

// ---------------- per-bucket sort -> padded per-node CSR + dinv + xp ------
// One block per bucket of 64 nodes. Per-node lists padded to mult of 8 with
// dummy src ZROW. Also writes xp[v] = (half)(dinv[v]*x[v]) for its nodes.
__global__ __launch_bounds__(256, 4) void k_sort(
    const int* __restrict__ bins, const int* __restrict__ boff,
    const float* __restrict__ x,
    ushort_t* __restrict__ srcp, int2* __restrict__ rowiv,
    float* __restrict__ dinv, __half* __restrict__ xp) {
  __shared__ int dg[64], lo[64], cur[64];
  __shared__ float sdin[64];
  __shared__ int Tsh;
  __shared__ ushort_t buf[8192];
  int tid = threadIdx.x, b = blockIdx.x;
  int start = boff[b], end = boff[b + 1];
  if (tid < 64) dg[tid] = 0;
  __syncthreads();
  for (int i = start + tid; i < end; i += 256)
    atomicAdd(&dg[bins[i] >> 16], 1);
  __syncthreads();
  int pdv = 0;
  if (tid < 64) { pdv = (dg[tid] + 7) & ~7; lo[tid] = pdv; }
  __syncthreads();
  for (int off = 1; off < 64; off <<= 1) {
    int u = 0;
    if (tid < 64 && tid >= off) u = lo[tid - off];
    __syncthreads();
    if (tid < 64) lo[tid] += u;
    __syncthreads();
  }
  int ex = 0;
  if (tid < 64) {
    ex = lo[tid] - pdv;       // exclusive padded offset
    cur[tid] = ex;
    if (tid == 63) Tsh = lo[63];
  }
  __syncthreads();
  int T = Tsh;
  int base = start + b * 512;  // 512 >= 64*7 max padding slack per bucket
  for (int i = tid; i < T; i += 256) buf[i] = (ushort_t)ZROW;
  __syncthreads();
  for (int i = start + tid; i < end; i += 256) {
    int v = bins[i];
    int dl = v >> 16;
    int p = atomicAdd(&cur[dl], 1);
    buf[p] = (ushort_t)(v & 0xFFFF);
  }
  __syncthreads();
  for (int i = tid; i < T; i += 256) srcp[base + i] = buf[i];
  if (tid < 64) {
    int v = b * 64 + tid;
    if (v < N_NODES) {
      rowiv[v] = make_int2(base + ex, pdv);
      float dv = rsqrtf((float)dg[tid] + 2.0f);
      dinv[v] = dv;
      sdin[tid] = dv;
    } else {
      sdin[tid] = 0.f;
    }
  }
  __syncthreads();
  int nb64 = b * 4096;  // b*64*64
  for (int idx = tid; idx < 4096; idx += 256) {
    int v = b * 64 + (idx >> 6);
    if (v < N_NODES) xp[nb64 + idx] = __float2half(sdin[idx >> 6] * x[nb64 + idx]);
  }
  if (b == 0 && tid < 64) xp[ZROW * 64 + tid] = __float2half(0.f);
}

// ---------------- weight composition ----------------
__global__ void k_compose(const float* __restrict__ Wz, const float* __restrict__ bz,
                          const float* __restrict__ Wlz, const float* __restrict__ blz,
                          const float* __restrict__ Wh, const float* __restrict__ bh,
                          const float* __restrict__ Wlh, const float* __restrict__ blh,
                          float2* __restrict__ M, float2* __restrict__ B2) {
  int t = blockIdx.x * 256 + threadIdx.x;
  if (t < 4096) {
    int i = t >> 6, c = t & 63;
    float mz = 0.f, mh = 0.f;
    for (int j = 0; j < 64; ++j) {
      mz = fmaf(Wz[i * 64 + j], Wlz[j * 64 + c], mz);
      mh = fmaf(Wh[i * 64 + j], Wlh[j * 64 + c], mh);
    }
    M[t] = make_float2(mz, mh);
  } else if (t < 4160) {
    int c = t - 4096;
    float vz = blz[c], vh = blh[c];
    for (int j = 0; j < 64; ++j) {
      vz = fmaf(bz[j], Wlz[j * 64 + c], vz);
      vh = fmaf(bh[j], Wlh[j * 64 + c], vh);
    }
    B2[c] = make_float2(vz, vh);
  }
}

// ---------------- gather: one wave per node, register accumulate ----------
// sx[v][c] = dinv[v]*sum_e xp[src_e][c] + 2*dinv[v]*xp[v][c]   (xp fp16)
__global__ __launch_bounds__(256) void k_agg(
    const ushort_t* __restrict__ srcp, const int2* __restrict__ rowiv,
    const float* __restrict__ dinv, const __half* __restrict__ xp,
    float* __restrict__ sxg) {
  int tid = threadIdx.x;
  int lane = tid & 63;
  int w = blockIdx.x * 4 + (tid >> 6);
  int nw = gridDim.x * 4;
  for (int v = w; v < N_NODES; v += nw) {
    int vu = __builtin_amdgcn_readfirstlane(v);
    int2 ri = rowiv[vu];
    int beg = ri.x, pd = ri.y;
    float a0 = 0.f, a1 = 0.f;
    for (int e = beg; e < beg + pd; e += 64) {
      int rem = beg + pd - e;
      int m = rem < 64 ? rem : 64;   // multiple of 8
      int sv = ZROW;
      if (lane < m) sv = srcp[e + lane];
      for (int j = 0; j < m; j += 8) {
        int s0 = rlanei(sv, j),     s1 = rlanei(sv, j + 1);
        int s2 = rlanei(sv, j + 2), s3 = rlanei(sv, j + 3);
        int s4 = rlanei(sv, j + 4), s5 = rlanei(sv, j + 5);
        int s6 = rlanei(sv, j + 6), s7 = rlanei(sv, j + 7);
        a0 += __half2float(xp[s0 * 64 + lane]);
        a1 += __half2float(xp[s1 * 64 + lane]);
        a0 += __half2float(xp[s2 * 64 + lane]);
        a1 += __half2float(xp[s3 * 64 + lane]);
        a0 += __half2float(xp[s4 * 64 + lane]);
        a1 += __half2float(xp[s5 * 64 + lane]);
        a0 += __half2float(xp[s6 * 64 + lane]);
        a1 += __half2float(xp[s7 * 64 + lane]);
      }
    }
    float dv = dinv[vu];
    float self = __half2float(xp[vu * 64 + lane]);
    sxg[vu * 64 + lane] = dv * (a0 + a1) + 2.f * dv * self;
  }
}

// ---------------- cell + readout (512 thr = 8 waves, 3 blk/CU) -----------
__global__ __launch_bounds__(512, 6) void k_cell(
    const float* __restrict__ sxg,
    const float2* __restrict__ M, const float2* __restrict__ B2,
    const float* __restrict__ Wout, const float* __restrict__ bout,
    float* __restrict__ out) {
  __shared__ float2 sM[4096];   // 32 KB
  __shared__ float sW[2880];    // 11.25 KB
  __shared__ float2 sB[64];
  __shared__ float sbo[48];
  int tid = threadIdx.x;
  for (int i = tid; i < 4096; i += 512) sM[i] = M[i];
  for (int i = tid; i < 2880; i += 512) sW[i] = Wout[i];
  if (tid < 64) sB[tid] = B2[tid];
  if (tid >= 64 && tid < 109) sbo[tid - 64] = bout[tid - 64];
  __syncthreads();

  int lane = tid & 63;
  int wv = tid >> 6;            // 0..7
  int nb = blockIdx.x * 64;

  for (int g = 0; g < 2; ++g) {
    int dl0 = wv * 8 + g * 4;   // 8 waves x 8 nodes = 64
    float sx[4];
    #pragma unroll
    for (int n = 0; n < 4; ++n) {
      int v = nb + dl0 + n;
      sx[n] = (v < N_NODES) ? sxg[v * 64 + lane] : 0.f;
    }
    float z[4], h[4];
    #pragma unroll
    for (int n = 0; n < 4; ++n) { z[n] = sB[lane].x; h[n] = sB[lane].y; }
    #pragma unroll 8
    for (int k = 0; k < 64; ++k) {
      float2 wvv = sM[k * 64 + lane];
      #pragma unroll
      for (int n = 0; n < 4; ++n) {
        float sk = rlanef(sx[n], k);
        z[n] = fmaf(sk, wvv.x, z[n]);
        h[n] = fmaf(sk, wvv.y, h[n]);
      }
    }
    #pragma unroll
    for (int n = 0; n < 4; ++n) {
      float Z = 1.f / (1.f + __expf(-z[n]));
      float t = fminf(15.f, fmaxf(-15.f, h[n]));
      float e2 = __expf(-2.f * t);
      float Th = (1.f - e2) / (1.f + e2);
      sx[n] = fmaxf((1.f - Z) * Th, 0.f);   // relu((1-Z)*tanh(h))
    }
    float o[4] = {0.f, 0.f, 0.f, 0.f};
    #pragma unroll 8
    for (int k = 0; k < 64; ++k) {
      float wvv = (lane < 45) ? sW[k * 45 + lane] : 0.f;
      #pragma unroll
      for (int n = 0; n < 4; ++n) {
        float hk = rlanef(sx[n], k);
        o[n] = fmaf(hk, wvv, o[n]);
      }
    }
    if (lane < 45) {
      #pragma unroll
      for (int n = 0; n < 4; ++n) {
        int v = nb + dl0 + n;
        if (v < N_NODES) out[v * 45 + lane] = o[n] + sbo[lane];
      }
    }
  }
}

// ---------------- launch ----------------
extern "C" void kernel_launch(void* const* d_in, const int* in_sizes, int n_in,
                              void* d_out, int out_size, void* d_ws, size_t ws_size,
                              hipStream_t stream) {
  const float* x    = (const float*)d_in[0];
  const int*   ei   = (const int*)d_in[1];
  const float* Wz   = (const float*)d_in[2];
  const float* bz   = (const float*)d_in[3];
  const float* Wlz  = (const float*)d_in[4];
  const float* blz  = (const float*)d_in[5];
  // d_in[6..9] (W_r branch) dead: H=0 => H*R=0.
  const float* Wh   = (const float*)d_in[10];
  const float* bh   = (const float*)d_in[11];
  const float* Wlh  = (const float*)d_in[12];
  const float* blh  = (const float*)d_in[13];
  const float* Wout = (const float*)d_in[14];
  const float* bout = (const float*)d_in[15];
  float* out = (float*)d_out;

  char* w = (char*)d_ws;
  // region [0, 12.8MB): cnt+bins early, sxg late (no temporal overlap)
  int*      cnt   = (int*)(w + 0);            // 200192 ints (0.8 MB)
  int*      bins  = (int*)(w + 800768);       // 1.6M ints (6.4 MB)
  float*    sxg   = (float*)(w + 0);          // 12.8 MB (aliases cnt+bins)
  ushort_t* srcp  = (ushort_t*)(w + 12800000);// ~4.0 MB
  int2*     rowiv = (int2*)(w + 16801024);    // 0.4 MB
  float*    dinv  = (float*)(w + 17201024);   // 0.2 MB
  int*      bsum  = (int*)(w + 17401024);     // 782 ints
  int*      boff  = (int*)(w + 17404160);     // 783 ints
  float2*   M     = (float2*)(w + 17407360);  // 32 KB
  float2*   B2    = (float2*)(w + 17440128);  // 512 B
  __half*   xp    = (__half*)(w + 17440768);  // 50001*64*2 = 6.4 MB
  // total ~23.9 MB

  k_hist <<<NBB, 256, 0, stream>>>(ei, cnt);
  k_scanA<<<NB, 256, 0, stream>>>(cnt, bsum);
  k_scanB<<<1, 1024, 0, stream>>>(bsum, boff);
  k_scanC<<<NB, 256, 0, stream>>>(cnt, boff);
  k_bin  <<<NBB, 256, 0, stream>>>(ei, cnt, bins);
  k_sort <<<NB, 256, 0, stream>>>(bins, boff, x, srcp, rowiv, dinv, xp);
  k_compose<<<17, 256, 0, stream>>>(Wz, bz, Wlz, blz, Wh, bh, Wlh, blh, M, B2);
  k_agg  <<<2048, 256, 0, stream>>>(srcp, rowiv, dinv, xp, sxg);
  k_cell <<<NB, 512, 0, stream>>>(sxg, M, B2, Wout, bout, out);
}

// Round 5
// 191.791 us; speedup vs baseline: 4.4192x; 1.2366x over previous
//
#include <hip/hip_runtime.h>

#define N_NODES 50000
#define N_EDGES 1600000
#define NB 782            // buckets of 64 dst nodes: ceil(50000/64)
#define NBB 256           // binning blocks
#define CHUNK 6250        // N_EDGES / NBB (exact)
#define ZROW 50000        // dummy src row (all zeros) for padding
#define NTILES 3125       // 50000 / 16 exact

typedef unsigned short ushort_t;
typedef _Float16 v8h __attribute__((ext_vector_type(8)));
typedef float f32x4_t __attribute__((ext_vector_type(4)));

// ---------------- helpers ----------------
__device__ __forceinline__ int rlanei(int v, int l) {
  return __builtin_amdgcn_readlane(v, l);
}

// ---------------- pass 1: per-(bucket,block) histogram ----------------
__global__ void k_hist(const int* __restrict__ ei, int* __restrict__ cnt) {
  __shared__ int h[NB];
  int tid = threadIdx.x, blk = blockIdx.x;
  for (int i = tid; i < NB; i += 256) h[i] = 0;
  __syncthreads();
  int base = blk * CHUNK;
  for (int i = base + tid; i < base + CHUNK; i += 256)
    atomicAdd(&h[ei[N_EDGES + i] >> 6], 1);
  __syncthreads();
  for (int b = tid; b < NB; b += 256) cnt[b * NBB + blk] = h[b];
}

// ---------------- scans ----------------
__global__ void k_scanA(const int* __restrict__ cnt, int* __restrict__ bsum) {
  __shared__ int sm[256];
  int t = threadIdx.x;
  sm[t] = cnt[blockIdx.x * 256 + t];
  __syncthreads();
  for (int off = 128; off > 0; off >>= 1) {
    if (t < off) sm[t] += sm[t + off];
    __syncthreads();
  }
  if (t == 0) bsum[blockIdx.x] = sm[0];
}

__global__ void k_scanB(const int* __restrict__ bsum, int* __restrict__ boff) {
  __shared__ int sm[1024];
  int t = threadIdx.x;
  int v = (t < NB) ? bsum[t] : 0;
  sm[t] = v;
  __syncthreads();
  for (int off = 1; off < 1024; off <<= 1) {
    int u = (t >= off) ? sm[t - off] : 0;
    __syncthreads();
    sm[t] += u;
    __syncthreads();
  }
  if (t < NB) boff[t] = sm[t] - v;  // exclusive bucket start
  if (t == 0) boff[NB] = N_EDGES;
}

__global__ void k_scanC(int* __restrict__ cnt, const int* __restrict__ boff) {
  __shared__ int sm[256];
  int t = threadIdx.x, j = blockIdx.x;
  int v = cnt[j * 256 + t];
  sm[t] = v;
  __syncthreads();
  for (int off = 1; off < 256; off <<= 1) {
    int u = (t >= off) ? sm[t - off] : 0;
    __syncthreads();
    sm[t] += u;
    __syncthreads();
  }
  cnt[j * 256 + t] = boff[j] + sm[t] - v;
}

// ---------------- pass 2: binned scatter (block-private regions) ----------
__global__ void k_bin(const int* __restrict__ ei, const int* __restrict__ offs,
                      int* __restrict__ bins) {
  __shared__ int cur[NB];
  int tid = threadIdx.x, blk = blockIdx.x;
  for (int b = tid; b < NB; b += 256) cur[b] = offs[b * NBB + blk];
  __syncthreads();
  int base = blk * CHUNK;
  for (int i = base + tid; i < base + CHUNK; i += 256) {
    int s = ei[i];
    int d = ei[N_EDGES + i];
    int b = d >> 6;
    int p = atomicAdd(&cur[b], 1);
    bins[p] = s | ((d & 63) << 16);   // src < 65536 fits 16 bits
  }
}

// ---------------- per-bucket sort -> padded per-node CSR + dinv + xp ------
__global__ __launch_bounds__(256, 4) void k_sort(
    const int* __restrict__ bins, const int* __restrict__ boff,
    const float* __restrict__ x,
    ushort_t* __restrict__ srcp, int2* __restrict__ rowiv,
    float* __restrict__ dinv, _Float16* __restrict__ xp) {
  __shared__ int dg[64], lo[64], cur[64];
  __shared__ float sdin[64];
  __shared__ int Tsh;
  __shared__ ushort_t buf[8192];
  int tid = threadIdx.x, b = blockIdx.x;
  int start = boff[b], end = boff[b + 1];
  if (tid < 64) dg[tid] = 0;
  __syncthreads();
  for (int i = start + tid; i < end; i += 256)
    atomicAdd(&dg[bins[i] >> 16], 1);
  __syncthreads();
  int pdv = 0;
  if (tid < 64) { pdv = (dg[tid] + 7) & ~7; lo[tid] = pdv; }
  __syncthreads();
  for (int off = 1; off < 64; off <<= 1) {
    int u = 0;
    if (tid < 64 && tid >= off) u = lo[tid - off];
    __syncthreads();
    if (tid < 64) lo[tid] += u;
    __syncthreads();
  }
  int ex = 0;
  if (tid < 64) {
    ex = lo[tid] - pdv;       // exclusive padded offset
    cur[tid] = ex;
    if (tid == 63) Tsh = lo[63];
  }
  __syncthreads();
  int T = Tsh;
  int base = start + b * 512;  // 512 >= 64*7 max padding slack per bucket
  for (int i = tid; i < T; i += 256) buf[i] = (ushort_t)ZROW;
  __syncthreads();
  for (int i = start + tid; i < end; i += 256) {
    int v = bins[i];
    int dl = v >> 16;
    int p = atomicAdd(&cur[dl], 1);
    buf[p] = (ushort_t)(v & 0xFFFF);
  }
  __syncthreads();
  for (int i = tid; i < T; i += 256) srcp[base + i] = buf[i];
  if (tid < 64) {
    int v = b * 64 + tid;
    if (v < N_NODES) {
      rowiv[v] = make_int2(base + ex, pdv);
      float dv = rsqrtf((float)dg[tid] + 2.0f);
      dinv[v] = dv;
      sdin[tid] = dv;
    } else {
      sdin[tid] = 0.f;
    }
  }
  __syncthreads();
  int nb64 = b * 4096;  // b*64*64
  for (int idx = tid; idx < 4096; idx += 256) {
    int v = b * 64 + (idx >> 6);
    if (v < N_NODES) xp[nb64 + idx] = (_Float16)(sdin[idx >> 6] * x[nb64 + idx]);
  }
  if (b == 0 && tid < 64) xp[ZROW * 64 + tid] = (_Float16)0.f;
}

// ---------------- weight composition (fp32 fused weights) ----------------
__global__ void k_compose(const float* __restrict__ Wz, const float* __restrict__ bz,
                          const float* __restrict__ Wlz, const float* __restrict__ blz,
                          const float* __restrict__ Wh, const float* __restrict__ bh,
                          const float* __restrict__ Wlh, const float* __restrict__ blh,
                          float2* __restrict__ M, float2* __restrict__ B2) {
  int t = blockIdx.x * 256 + threadIdx.x;
  if (t < 4096) {
    int i = t >> 6, c = t & 63;
    float mz = 0.f, mh = 0.f;
    for (int j = 0; j < 64; ++j) {
      mz = fmaf(Wz[i * 64 + j], Wlz[j * 64 + c], mz);
      mh = fmaf(Wh[i * 64 + j], Wlh[j * 64 + c], mh);
    }
    M[t] = make_float2(mz, mh);
  } else if (t < 4160) {
    int c = t - 4096;
    float vz = blz[c], vh = blh[c];
    for (int j = 0; j < 64; ++j) {
      vz = fmaf(bz[j], Wlz[j * 64 + c], vz);
      vh = fmaf(bh[j], Wlh[j * 64 + c], vh);
    }
    B2[c] = make_float2(vz, vh);
  }
}

// ---------------- pack weights into MFMA B-fragment order (fp16) ---------
// B-frag layout for mfma_f32_16x16x32_f16: lane holds B[k=ks*32+(lane>>4)*8+j]
// [n=ntile*16+(lane&15)], j=0..7. Stored frag-major: ((ntile*2+ks)*64+lane)*8+j
// Bzh: N=128 (cols 0..63 = z-weights Mz, 64..127 = h-weights Mh), 8 ntiles.
// Bwo: N=48 (Wout cols, zero-padded 45..47), 3 ntiles.
__global__ void k_pack(const float2* __restrict__ M, const float* __restrict__ Wout,
                       _Float16* __restrict__ Bzh, _Float16* __restrict__ Bwo) {
  int t = blockIdx.x * 256 + threadIdx.x;
  if (t < 8192) {
    int frag = t >> 9, lane = (t >> 3) & 63, j = t & 7;
    int ntile = frag >> 1, ks = frag & 1;
    int n = ntile * 16 + (lane & 15);
    int k = ks * 32 + ((lane >> 4) << 3) + j;
    float v = (n < 64) ? M[k * 64 + n].x : M[k * 64 + (n - 64)].y;
    Bzh[t] = (_Float16)v;
  } else if (t < 11264) {
    int u = t - 8192;
    int frag = u >> 9, lane = (u >> 3) & 63, j = u & 7;
    int ntile = frag >> 1, ks = frag & 1;
    int n = ntile * 16 + (lane & 15);
    int k = ks * 32 + ((lane >> 4) << 3) + j;
    Bwo[u] = (_Float16)((n < 45) ? Wout[k * 45 + n] : 0.f);
  }
}

// ---------------- gather: one wave per node, register accumulate ----------
__global__ __launch_bounds__(256) void k_agg(
    const ushort_t* __restrict__ srcp, const int2* __restrict__ rowiv,
    const float* __restrict__ dinv, const _Float16* __restrict__ xp,
    _Float16* __restrict__ sxg) {
  int tid = threadIdx.x;
  int lane = tid & 63;
  int w = blockIdx.x * 4 + (tid >> 6);
  int nw = gridDim.x * 4;
  for (int v = w; v < N_NODES; v += nw) {
    int vu = __builtin_amdgcn_readfirstlane(v);
    int2 ri = rowiv[vu];
    int beg = ri.x, pd = ri.y;
    float a0 = 0.f, a1 = 0.f;
    for (int e = beg; e < beg + pd; e += 64) {
      int rem = beg + pd - e;
      int m = rem < 64 ? rem : 64;   // multiple of 8
      int sv = ZROW;
      if (lane < m) sv = srcp[e + lane];
      for (int j = 0; j < m; j += 8) {
        int s0 = rlanei(sv, j),     s1 = rlanei(sv, j + 1);
        int s2 = rlanei(sv, j + 2), s3 = rlanei(sv, j + 3);
        int s4 = rlanei(sv, j + 4), s5 = rlanei(sv, j + 5);
        int s6 = rlanei(sv, j + 6), s7 = rlanei(sv, j + 7);
        a0 += (float)xp[s0 * 64 + lane];
        a1 += (float)xp[s1 * 64 + lane];
        a0 += (float)xp[s2 * 64 + lane];
        a1 += (float)xp[s3 * 64 + lane];
        a0 += (float)xp[s4 * 64 + lane];
        a1 += (float)xp[s5 * 64 + lane];
        a0 += (float)xp[s6 * 64 + lane];
        a1 += (float)xp[s7 * 64 + lane];
      }
    }
    float dv = dinv[vu];
    float self = (float)xp[vu * 64 + lane];
    sxg[vu * 64 + lane] = (_Float16)(dv * (a0 + a1) + 2.f * dv * self);
  }
}

// ---------------- MFMA cell + readout ----------------
// One wave per 16-node tile (50000 = 3125 exact tiles). A = sx (fp16),
// B-frags in VGPRs. z|h GEMM (16 MFMA), nonlinearity on C-frags,
// wave-private LDS transpose (C-layout -> A-layout), readout GEMM (6 MFMA).
__global__ __launch_bounds__(256) void k_cell(
    const _Float16* __restrict__ sxg, const _Float16* __restrict__ Bzh,
    const _Float16* __restrict__ Bwo, const float2* __restrict__ B2,
    const float* __restrict__ bout, float* __restrict__ out) {
  __shared__ __align__(16) _Float16 tbuf[4][16][72];  // 72: pad rows (bank)
  int tid = threadIdx.x;
  int lane = tid & 63, wv = tid >> 6;
  int l15 = lane & 15, quad = lane >> 4;
  int tile = blockIdx.x * 4 + wv;
  if (tile >= NTILES) return;    // no barriers in this kernel -> safe

  // ---- preload B fragments into VGPRs ----
  v8h bz[8][2], bw[3][2];
  #pragma unroll
  for (int t = 0; t < 8; ++t)
    #pragma unroll
    for (int ks = 0; ks < 2; ++ks)
      bz[t][ks] = *(const v8h*)(Bzh + (((t * 2 + ks) * 64 + lane) << 3));
  #pragma unroll
  for (int t = 0; t < 3; ++t)
    #pragma unroll
    for (int ks = 0; ks < 2; ++ks)
      bw[t][ks] = *(const v8h*)(Bwo + (((t * 2 + ks) * 64 + lane) << 3));
  float zb[4], hb[4], ob[3];
  #pragma unroll
  for (int t = 0; t < 4; ++t) {
    float2 bb = B2[t * 16 + l15];
    zb[t] = bb.x; hb[t] = bb.y;
  }
  #pragma unroll
  for (int t = 0; t < 3; ++t) {
    int c = t * 16 + l15;
    ob[t] = (c < 45) ? bout[c] : 0.f;
  }

  // ---- A fragments: A[m=l15][k=quad*8+j] ----
  const _Float16* ar = sxg + (tile * 16 + l15) * 64 + quad * 8;
  v8h a0 = *(const v8h*)ar;
  v8h a1 = *(const v8h*)(ar + 32);

  // ---- z|h GEMM: C[16 nodes][128] ----
  f32x4_t accz[8];
  #pragma unroll
  for (int t = 0; t < 8; ++t) {
    f32x4_t c4 = {0.f, 0.f, 0.f, 0.f};
    c4 = __builtin_amdgcn_mfma_f32_16x16x32_f16(a0, bz[t][0], c4, 0, 0, 0);
    c4 = __builtin_amdgcn_mfma_f32_16x16x32_f16(a1, bz[t][1], c4, 0, 0, 0);
    accz[t] = c4;
  }

  // ---- nonlinearity; write relu((1-Z)*tanh(h)) to LDS in C-layout ----
  // C/D: col = t*16+l15, row = quad*4+r
  #pragma unroll
  for (int t = 0; t < 4; ++t) {
    #pragma unroll
    for (int r = 0; r < 4; ++r) {
      float zv = accz[t][r] + zb[t];
      float hv = accz[t + 4][r] + hb[t];
      float Z = 1.f / (1.f + __expf(-zv));
      float tt = fminf(15.f, fmaxf(-15.f, hv));
      float e2 = __expf(-2.f * tt);
      float Th = (1.f - e2) / (1.f + e2);
      tbuf[wv][quad * 4 + r][t * 16 + l15] = (_Float16)fmaxf((1.f - Z) * Th, 0.f);
    }
  }
  __asm__ volatile("s_waitcnt lgkmcnt(0)" ::: "memory");  // wave-local LDS fence

  // ---- read back in A-layout: A[m=l15][k=quad*8+j] ----
  v8h p0 = *(const v8h*)&tbuf[wv][l15][quad * 8];
  v8h p1 = *(const v8h*)&tbuf[wv][l15][32 + quad * 8];

  // ---- readout GEMM: out[16 nodes][48] ----
  #pragma unroll
  for (int t = 0; t < 3; ++t) {
    f32x4_t o4 = {0.f, 0.f, 0.f, 0.f};
    o4 = __builtin_amdgcn_mfma_f32_16x16x32_f16(p0, bw[t][0], o4, 0, 0, 0);
    o4 = __builtin_amdgcn_mfma_f32_16x16x32_f16(p1, bw[t][1], o4, 0, 0, 0);
    int c = t * 16 + l15;
    if (c < 45) {
      #pragma unroll
      for (int r = 0; r < 4; ++r)
        out[(tile * 16 + quad * 4 + r) * 45 + c] = o4[r] + ob[t];
    }
  }
}

// ---------------- launch ----------------
extern "C" void kernel_launch(void* const* d_in, const int* in_sizes, int n_in,
                              void* d_out, int out_size, void* d_ws, size_t ws_size,
                              hipStream_t stream) {
  const float* x    = (const float*)d_in[0];
  const int*   ei   = (const int*)d_in[1];
  const float* Wz   = (const float*)d_in[2];
  const float* bz   = (const float*)d_in[3];
  const float* Wlz  = (const float*)d_in[4];
  const float* blz  = (const float*)d_in[5];
  // d_in[6..9] (W_r branch) dead: H=0 => H*R=0.
  const float* Wh   = (const float*)d_in[10];
  const float* bh   = (const float*)d_in[11];
  const float* Wlh  = (const float*)d_in[12];
  const float* blh  = (const float*)d_in[13];
  const float* Wout = (const float*)d_in[14];
  const float* bout = (const float*)d_in[15];
  float* out = (float*)d_out;

  char* w = (char*)d_ws;
  // region [0, 12.8MB): cnt+bins early, sxg (fp16) late (no temporal overlap)
  int*      cnt   = (int*)(w + 0);            // 0.8 MB
  int*      bins  = (int*)(w + 800768);       // 6.4 MB
  _Float16* sxg   = (_Float16*)(w + 0);       // 6.4 MB (aliases cnt+bins)
  ushort_t* srcp  = (ushort_t*)(w + 12800000);// ~4.0 MB
  int2*     rowiv = (int2*)(w + 16801024);    // 0.4 MB
  float*    dinv  = (float*)(w + 17201024);   // 0.2 MB
  int*      bsum  = (int*)(w + 17401024);     // 782 ints
  int*      boff  = (int*)(w + 17404160);     // 783 ints
  float2*   M     = (float2*)(w + 17407360);  // 32 KB
  float2*   B2    = (float2*)(w + 17440128);  // 512 B
  _Float16* Bzh   = (_Float16*)(w + 17440768);// 16 KB
  _Float16* Bwo   = (_Float16*)(w + 17457152);// 6 KB
  _Float16* xp    = (_Float16*)(w + 17463296);// 6.4 MB
  // total ~23.9 MB

  k_hist <<<NBB, 256, 0, stream>>>(ei, cnt);
  k_scanA<<<NB, 256, 0, stream>>>(cnt, bsum);
  k_scanB<<<1, 1024, 0, stream>>>(bsum, boff);
  k_scanC<<<NB, 256, 0, stream>>>(cnt, boff);
  k_bin  <<<NBB, 256, 0, stream>>>(ei, cnt, bins);
  k_sort <<<NB, 256, 0, stream>>>(bins, boff, x, srcp, rowiv, dinv, xp);
  k_compose<<<17, 256, 0, stream>>>(Wz, bz, Wlz, blz, Wh, bh, Wlh, blh, M, B2);
  k_pack <<<44, 256, 0, stream>>>(M, Wout, Bzh, Bwo);
  k_agg  <<<2048, 256, 0, stream>>>(srcp, rowiv, dinv, xp, sxg);
  k_cell <<<NB, 256, 0, stream>>>(sxg, Bzh, Bwo, B2, bout, out);
}